// Round 10
// baseline (2701.283 us; speedup 1.0000x reference)
//
#include <hip/hip_runtime.h>
#include <math.h>

#define WW 512
#define HH 512
#define NPIX (WW*HH)
#define NSH 18  /* log2(NPIX) */
#define NXCD 8

typedef unsigned long long u64;
typedef unsigned int u32;
typedef unsigned short u16;

__device__ __forceinline__ u64 umax64(u64 a, u64 b) { return a > b ? a : b; }

// image-slab task swizzle (bijection over [0,ntasks), ntasks % 8 == 0):
// consecutive task-eighths land on one XCD under the empirical blockIdx%8
// round-robin -> per-image state stays in one XCD's L2. Correctness does NOT
// depend on this mapping (barriers use agent-scope release/acquire).
__device__ __forceinline__ int swz_task(int raw, int ntasks) {
  return (raw & (NXCD - 1)) * (ntasks >> 3) + (raw >> 3);
}

// tile mapping for prep: 32x8 tiles, 1024/image (grid == ntasks there).
__device__ __forceinline__ void tile_coords(int& bb, int& x0, int& y0) {
  int t = swz_task((int)blockIdx.x, (int)gridDim.x);
  bb = t >> 10;
  int rem = t & 1023;
  y0 = (rem >> 4) << 3;   // tile row * 8
  x0 = (rem & 15) << 5;   // tile col * 32
}

// colors + gradient magnitude of pixel p (same __f*_rn sequence as always ->
// bit-identical to the reference's XLA lowering)
__device__ __forceinline__ float d_colg(const float* __restrict__ fb, int p, int pw, int ph,
                                        float col[3]) {
  float s = 0.f;
#pragma unroll
  for (int c = 0; c < 3; ++c) {
    const float* fc = fb + (size_t)c * NPIX;
    float v = fc[p];
    col[c] = v;
    float gx = (pw < WW - 1) ? __fsub_rn(fc[p + 1], v) : 0.f;
    float gy = (ph < HH - 1) ? __fsub_rn(fc[p + WW], v) : 0.f;
    float g = __fsqrt_rn(__fadd_rn(__fadd_rn(__fmul_rn(gx, gx), __fmul_rn(gy, gy)), 1e-12f));
    s = __fadd_rn(s, g);
  }
  return __fdiv_rn(s, 3.0f);
}

// sim bits (<<32): bitwise symmetric, one exp per undirected edge; bits 62-63
// carry the level tag (atomicMax monotone in tag -> no inter-level zeroing).
__device__ __forceinline__ u64 d_simbits(float4 a, float4 b) {
  float d0 = __fsub_rn(a.x, b.x);
  float d1 = __fsub_rn(a.y, b.y);
  float d2 = __fsub_rn(a.z, b.z);
  float ss = __fadd_rn(__fadd_rn(__fmul_rn(d0, d0), __fmul_rn(d1, d1)), __fmul_rn(d2, d2));
  float dc = __fsqrt_rn(__fadd_rn(ss, 1e-12f));
  float ge = __fmul_rn(0.5f, __fadd_rn(a.w, b.w));
  float t = __fadd_rn(__fdiv_rn(dc, 10.0f), __fdiv_rn(ge, 27.8f));
  float sim = (float)exp(-(double)t);   // ~correctly-rounded expf
  return ((u64)__float_as_uint(sim)) << 32;
}

// FUSED prep + level-0 edge + level-0 scan/merge (round-9 kernel, verbatim).
__global__ __launch_bounds__(256) void k_prep0(const float* __restrict__ feat,
                                               int* __restrict__ labels,
                                               int* __restrict__ cnt,
                                               float4* __restrict__ pix4,
                                               float4* __restrict__ mcol4,
                                               u16* __restrict__ mem,
                                               u64* __restrict__ bnkey) {
  __shared__ float4 scolg[432];   // 36 x 12: cx in [-2,33], cy in [-2,9]
  __shared__ u64 skey[256];
  int bb, x0, y0;
  tile_coords(bb, x0, y0);
  const float* fb = feat + (size_t)bb * 3 * NPIX;
  int tid = (int)threadIdx.x;
  skey[tid] = 0;
  for (int c = tid; c < 432; c += 256) {
    int cx = (c % 36) - 2, cy = (c / 36) - 2;
    int x = x0 + cx, y = y0 + cy;
    if (x >= 0 && x < WW && y >= 0 && y < HH) {
      float col[3];
      float g = d_colg(fb, y * WW + x, x, y, col);
      scolg[c] = make_float4(col[0], col[1], col[2], g);
    }
  }
  __syncthreads();
  int tx = tid & 31, ty = tid >> 5;
  int x = x0 + tx, y = y0 + ty;
  int n = y * WW + x;
  int idx = (bb << NSH) + n;
  int cc = (ty + 2) * 36 + (tx + 2);
  float4 ca = scolg[cc];
  pix4[idx] = ca;
  u64 key = 0;
  if (x < WW - 1) {              // right edge (shared in-tile)
    u64 s = d_simbits(ca, scolg[cc + 1]);
    key = umax64(key, s | (u32)(NPIX - (n + 1)));
    if (tx < 31) atomicMax(&skey[tid + 1], s | (u32)(NPIX - n));
  }
  if (tx == 0 && x > 0)          // left boundary edge (solo)
    key = umax64(key, d_simbits(ca, scolg[cc - 1]) | (u32)(NPIX - (n - 1)));
  if (y < HH - 1) {              // down edge (shared in-tile)
    u64 s = d_simbits(ca, scolg[cc + 36]);
    key = umax64(key, s | (u32)(NPIX - (n + WW)));
    if (ty < 7) atomicMax(&skey[tid + 32], s | (u32)(NPIX - n));
  }
  if (ty == 0 && y > 0)          // up boundary edge (solo)
    key = umax64(key, d_simbits(ca, scolg[cc - 36]) | (u32)(NPIX - (n - WW)));
  __syncthreads();
  key = umax64(key, skey[tid]);  // own-slot read/write only -> no hazard
  bnkey[idx] = key;              // tag-0 init of the single key buffer
  skey[tid] = key;               // publish full key for in-tile lookups
  __syncthreads();

  int v = NPIX - (int)(key & 0xffffffffu);
  int vx = v & (WW - 1), vy = v >> 9;
  u64 kv;
  if (vx >= x0 && vx < x0 + 32 && vy >= y0 && vy < y0 + 8) {
    kv = skey[(vy - y0) * 32 + (vx - x0)];
  } else {
    int vc = (vy - y0 + 2) * 36 + (vx - x0 + 2);
    float4 cv = scolg[vc];
    kv = 0;
    if (vx < WW - 1) kv = umax64(kv, d_simbits(cv, scolg[vc + 1]) | (u32)(NPIX - (v + 1)));
    if (vx > 0)      kv = umax64(kv, d_simbits(cv, scolg[vc - 1]) | (u32)(NPIX - (v - 1)));
    if (vy < HH - 1) kv = umax64(kv, d_simbits(cv, scolg[vc + 36]) | (u32)(NPIX - (v + WW)));
    if (vy > 0)      kv = umax64(kv, d_simbits(cv, scolg[vc - 36]) | (u32)(NPIX - (v - WW)));
  }
  bool mutual = (NPIX - (int)(kv & 0xffffffffu)) == n;
  if (mutual) {
    if (n < v) {   // rep side: ascending-order mean (n then v), exact sequence
      float4 pb = scolg[(vy - y0 + 2) * 36 + (vx - x0 + 2)];
      float s0 = __fadd_rn(__fadd_rn(0.f, ca.x), pb.x);
      float s1 = __fadd_rn(__fadd_rn(0.f, ca.y), pb.y);
      float s2 = __fadd_rn(__fadd_rn(0.f, ca.z), pb.z);
      float sg = __fadd_rn(__fadd_rn(0.f, ca.w), pb.w);
      mcol4[idx] = make_float4(__fdiv_rn(s0, 2.0f), __fdiv_rn(s1, 2.0f),
                               __fdiv_rn(s2, 2.0f), __fdiv_rn(sg, 2.0f));
      labels[idx] = n;
      cnt[idx] = 2;
      u16* mo = mem + ((size_t)idx << 4);
      mo[0] = 0; mo[1] = (u16)(v - n);
    } else {       // absorbed side
      labels[idx] = v;
      cnt[idx] = 0;
      mcol4[idx] = ca;
    }
  } else {
    labels[idx] = n;
    cnt[idx] = 1;
    mcol4[idx] = ca;
  }
}

// grid barrier: per-phase counter, release-RMW + acquire-poll at agent scope.
// The release/acquire pair makes each block's plain stores visible across
// XCDs (G16-safe: no reliance on block->XCD mapping). Counter used once per
// launch; re-zeroed by a 64B memset each chunk.
__device__ __forceinline__ void gbar(int* c, int G) {
  __syncthreads();
  if (threadIdx.x == 0) {
    __hip_atomic_fetch_add(c, 1, __ATOMIC_ACQ_REL, __HIP_MEMORY_SCOPE_AGENT);
    while (__hip_atomic_load(c, __ATOMIC_ACQUIRE, __HIP_MEMORY_SCOPE_AGENT) < G)
      __builtin_amdgcn_s_sleep(8);
  }
  __syncthreads();
}

// PERSISTENT levels-1..3 pipeline + output: the round-9 k_edge / k_scanpairs /
// k_out bodies verbatim (returns -> guarded blocks), grid-strided over
// swizzled tasks, separated by 6 software grid barriers. Grid = min(2048,
// ntasks) blocks of 256 with __launch_bounds__(256,8): VGPR capped at 64
// (bodies use <=24), LDS 7168B -> 8 blocks/CU = exactly the 2048-thread/CU
// capacity -> all blocks co-resident by construction (no deadlock).
__global__ __launch_bounds__(256, 8) void k_levels(int* __restrict__ labels,
                                                   int* __restrict__ cnt,
                                                   u16* __restrict__ mem,
                                                   u64* __restrict__ bnkey,
                                                   const float4* __restrict__ pix4,
                                                   float4* __restrict__ mcol4,
                                                   float* __restrict__ out,
                                                   int total, int b0, int Btot,
                                                   int* __restrict__ bar) {
  // LDS union: edge phase {sla 1KB | sma 4KB | skey 2KB} = 7168B;
  // sp phase {swl 2KB | scnt 4B} overlays the same buffer.
  __shared__ __align__(16) char smem[7168];
  int*    sla  = (int*)smem;
  float4* sma  = (float4*)(smem + 1024);
  u64*    skey = (u64*)(smem + 5120);
  u64*    swl  = (u64*)smem;
  int*    scnt = (int*)(smem + 2048);
  const int ntasks = total >> 8;
  const int tid = (int)threadIdx.x;
  const int G = (int)gridDim.x;

  for (int lvl = 1; lvl <= 3; ++lvl) {
    // ---- edge phase (round-8/9 k_edge body + run-leader atomic dedup) ----
    for (int raw = (int)blockIdx.x; raw < ntasks; raw += G) {
      int t = swz_task(raw, ntasks);
      int bb = t >> 10;
      int rem = t & 1023;
      int y0 = (rem >> 4) << 3;
      int x0 = (rem & 15) << 5;
      int tx = tid & 31, ty = tid >> 5;
      int x = x0 + tx, y = y0 + ty;
      int n = y * WW + x;
      int base = bb << NSH;
      int idx = base + n;
      int la = labels[idx];
      float4 ma = mcol4[base + la];
      sla[tid] = la;
      sma[tid] = ma;
      skey[tid] = 0;
      __syncthreads();
      u64 key = 0;
      if (x < WW - 1) {              // right edge
        if (tx < 31) {
          int lb = sla[tid + 1];
          if (lb != la) {
            u64 s = d_simbits(ma, sma[tid + 1]);
            key = umax64(key, s | (u32)(NPIX - lb));
            atomicMax(&skey[tid + 1], s | (u32)(NPIX - la));
          }
        } else {
          int lb = labels[idx + 1];
          if (lb != la) key = umax64(key, d_simbits(ma, mcol4[base + lb]) | (u32)(NPIX - lb));
        }
      }
      if (tx == 0 && x > 0) {        // left boundary edge (solo)
        int lb = labels[idx - 1];
        if (lb != la) key = umax64(key, d_simbits(ma, mcol4[base + lb]) | (u32)(NPIX - lb));
      }
      if (y < HH - 1) {              // down edge
        if (ty < 7) {
          int lb = sla[tid + 32];
          if (lb != la) {
            u64 s = d_simbits(ma, sma[tid + 32]);
            key = umax64(key, s | (u32)(NPIX - lb));
            atomicMax(&skey[tid + 32], s | (u32)(NPIX - la));
          }
        } else {
          int lb = labels[idx + WW];
          if (lb != la) key = umax64(key, d_simbits(ma, mcol4[base + lb]) | (u32)(NPIX - lb));
        }
      }
      if (ty == 0 && y > 0) {        // up boundary edge (solo)
        int lb = labels[idx - WW];
        if (lb != la) key = umax64(key, d_simbits(ma, mcol4[base + lb]) | (u32)(NPIX - lb));
      }
      __syncthreads();
      u64 val = umax64(key, skey[tid]);
      skey[tid] = val;
      __syncthreads();
      bool leader = (tx == 0) || (sla[tid - 1] != la);
      if (leader) {
        u64 m2 = val;
        int t2 = tid + 1, txx = tx + 1;
        while (txx < 32 && sla[t2] == la) { m2 = umax64(m2, skey[t2]); ++t2; ++txx; }
        if (m2) atomicMax(&bnkey[base + la], ((u64)lvl << 62) | m2);
      }
      __syncthreads();   // protect LDS before next task iteration
    }
    gbar(&bar[2 * lvl - 2], G);

    // ---- scan+pairs phase (round-9 k_scanpairs body) ----
    const bool LAST = (lvl == 3);
    for (int raw = (int)blockIdx.x; raw < ntasks; raw += G) {
      int t = swz_task(raw, ntasks);
      if (tid == 0) *scnt = 0;
      __syncthreads();
      int idx = t * 256 + tid;
      bool pred = false;
      u64 e = 0;
      {
        int n = idx & (NPIX - 1);
        int base = idx - n;
        u64 K = bnkey[idx];
        if ((int)(K >> 62) == lvl) {             // tag==lvl => live rep
          int v = NPIX - (int)(K & 0xffffffffu);
          if (v < NPIX && n < v) {               // only the min side acts
            u64 Kv = bnkey[base + v];
            if ((int)(Kv >> 62) == lvl && NPIX - (int)(Kv & 0xffffffffu) == n) {
              pred = true;
              e = ((u64)(u32)idx << 32) | (u32)v;
            }
          }
        }
      }
      u64 mask = __ballot(pred);
      int lane = tid & 63;
      int wb0 = 0;
      if (lane == 0 && mask) wb0 = atomicAdd(scnt, __popcll(mask));
      int wb = __shfl(wb0, 0);
      if (pred) {
        int pos = wb + __popcll(mask & ((1ull << lane) - 1ull));
        swl[pos] = e;
      }
      __syncthreads();
      int m = *scnt;
      if (tid < m) {
        e = swl[tid];
        int idx2 = (int)(e >> 32);
        int v = (int)(e & 0xffffffffu);
        int n = idx2 & (NPIX - 1);
        int base = idx2 - n;
        u16* mo = mem + ((size_t)idx2 << 4);
        int c = cnt[idx2];
        int cb = cnt[base + v];
        const u16* ma = mem + ((size_t)idx2 << 4);
        const u16* mb = mem + ((size_t)(base + v) << 4);
        int k = c + cb;
        float s0 = 0.f, s1 = 0.f, s2 = 0.f, sg = 0.f;
        int i = 0, j = 0;
        while (i < c || j < cb) {
          int av = (i < c) ? ((c == 1) ? n : n + (int)ma[i]) : 0x7fffffff;
          int bv = (j < cb) ? ((cb == 1) ? v : v + (int)mb[j]) : 0x7fffffff;
          int xx;
          bool fromB;
          if (av < bv) { xx = av; ++i; fromB = false; } else { xx = bv; ++j; fromB = true; }
          float4 p = pix4[base + xx];
          s0 = __fadd_rn(s0, p.x);
          s1 = __fadd_rn(s1, p.y);
          s2 = __fadd_rn(s2, p.z);
          sg = __fadd_rn(sg, p.w);
          if (!LAST && fromB) labels[base + xx] = n;   // rep-side already labeled n
        }
        if (!LAST) {
          // descending in-place merged-list write (read-before-write safe)
          int i2 = c - 1, j2 = cb - 1;
          for (int t2 = k - 1; t2 >= 0; --t2) {
            int av = (i2 >= 0) ? ((c == 1) ? n : n + (int)ma[i2]) : (int)0x80000000;
            int bv = (j2 >= 0) ? ((cb == 1) ? v : v + (int)mb[j2]) : (int)0x80000000;
            int xx;
            if (av > bv) { xx = av; --i2; } else { xx = bv; --j2; }
            mo[t2] = (u16)(xx - n);
          }
        }
        float safe = (float)k;
        mcol4[idx2] = make_float4(__fdiv_rn(s0, safe), __fdiv_rn(s1, safe),
                                  __fdiv_rn(s2, safe), __fdiv_rn(sg, safe));
        if (LAST) {
          cnt[base + v] = -n;        // forwarding marker for the out phase
        } else {
          cnt[idx2] = k;
          cnt[base + v] = 0;
        }
      }
      __syncthreads();   // protect LDS before next task iteration
    }
    gbar(&bar[2 * lvl - 1], G);
  }

  // ---- output phase (round-9 k_out body) ----
  for (int raw = (int)blockIdx.x; raw < ntasks; raw += G) {
    int t = swz_task(raw, ntasks);
    int idx = t * 256 + tid;
    int b = idx >> NSH;
    int n = idx & (NPIX - 1);
    int base = b << NSH;
    int l = labels[idx];
    int c2 = cnt[base + l];
    if (c2 <= 0) l = -c2;
    out[(size_t)(b0 + b) * NPIX + n] = (float)l;
    size_t cb = (size_t)Btot * NPIX;
    float4 mm = mcol4[base + l];
    out[cb + ((size_t)(b0 + b) * 3 + 0) * NPIX + n] = mm.x;
    out[cb + ((size_t)(b0 + b) * 3 + 1) * NPIX + n] = mm.y;
    out[cb + ((size_t)(b0 + b) * 3 + 2) * NPIX + n] = mm.z;
  }
}

extern "C" void kernel_launch(void* const* d_in, const int* in_sizes, int n_in,
                              void* d_out, int out_size, void* d_ws, size_t ws_size,
                              hipStream_t stream) {
  const float* feat = (const float*)d_in[0];
  float* out = (float*)d_out;
  int Btot = in_sizes[0] / (3 * NPIX);

  int* bar = (int*)d_ws;                 // 6 barrier counters, 256B reserved
  char* wsb = (char*)d_ws + 256;
  // per-pixel ws bytes:
  //   mcol4 16 + pix4 16 + key 8 + labels 4 + cnt 4 + mem(u16x16) 32 = 80
  const size_t perB = (size_t)NPIX * 80;
  size_t avail = (ws_size > 256) ? (ws_size - 256) : 0;
  int nbmax = (int)(avail / perB);
  if (nbmax < 1) nbmax = 1;
  if (nbmax > Btot) nbmax = Btot;

  for (int b0 = 0; b0 < Btot; b0 += nbmax) {
    int nb = (Btot - b0 < nbmax) ? (Btot - b0) : nbmax;
    size_t cn = (size_t)nb << NSH;
    char* p = wsb;
    float4* mcol4 = (float4*)p; p += cn * 16;   // 16B-aligned first
    float4* pix4 = (float4*)p;  p += cn * 16;
    u64* key = (u64*)p;         p += cn * 8;
    int* labels = (int*)p;      p += cn * 4;
    int* cnt = (int*)p;         p += cn * 4;
    u16* mem = (u16*)p;

    const float* fchunk = feat + (size_t)b0 * 3 * NPIX;
    int total = (int)cn;
    int ntasks = total >> 8;            // nb*1024, divisible by 8
    int g2 = ntasks < 2048 ? ntasks : 2048;

    hipMemsetAsync(bar, 0, 64, stream);  // zero barrier counters (per launch)
    k_prep0<<<ntasks, 256, 0, stream>>>(fchunk, labels, cnt, pix4, mcol4, mem, key);
    k_levels<<<g2, 256, 0, stream>>>(labels, cnt, mem, key, pix4, mcol4, out,
                                     total, b0, Btot, bar);
  }
}

// Round 11
// 250.292 us; speedup vs baseline: 10.7925x; 10.7925x over previous
//
#include <hip/hip_runtime.h>
#include <math.h>

#define WW 512
#define HH 512
#define NPIX (WW*HH)
#define NSH 18  /* log2(NPIX) */
#define NXCD 8

typedef unsigned long long u64;
typedef unsigned int u32;
typedef unsigned short u16;

__device__ __forceinline__ u64 umax64(u64 a, u64 b) { return a > b ? a : b; }

// XCD-contiguous block remap for the 1-D kernels (scanpairs/out).
// Grid is always nb*1024 -> divisible by 8, so this is a bijection.
__device__ __forceinline__ int swz_idx() {
  int g = gridDim.x;
  int b = (int)blockIdx.x;
  int nb2 = (b & (NXCD - 1)) * (g >> 3) + (b >> 3);
  return nb2 * 256 + (int)threadIdx.x;
}

// tile mapping for the 2-D kernels: 32x8 tiles, 1024/image, XCD-slab swizzled.
__device__ __forceinline__ void tile_coords(int& bb, int& x0, int& y0) {
  int g = gridDim.x;
  int b = (int)blockIdx.x;
  int t = (b & (NXCD - 1)) * (g >> 3) + (b >> 3);
  bb = t >> 10;
  int rem = t & 1023;
  y0 = (rem >> 4) << 3;   // tile row * 8
  x0 = (rem & 15) << 5;   // tile col * 32
}

// colors + gradient magnitude of pixel p (same __f*_rn sequence as always ->
// bit-identical to the reference's XLA lowering)
__device__ __forceinline__ float d_colg(const float* __restrict__ fb, int p, int pw, int ph,
                                        float col[3]) {
  float s = 0.f;
#pragma unroll
  for (int c = 0; c < 3; ++c) {
    const float* fc = fb + (size_t)c * NPIX;
    float v = fc[p];
    col[c] = v;
    float gx = (pw < WW - 1) ? __fsub_rn(fc[p + 1], v) : 0.f;
    float gy = (ph < HH - 1) ? __fsub_rn(fc[p + WW], v) : 0.f;
    float g = __fsqrt_rn(__fadd_rn(__fadd_rn(__fmul_rn(gx, gx), __fmul_rn(gy, gy)), 1e-12f));
    s = __fadd_rn(s, g);
  }
  return __fdiv_rn(s, 3.0f);
}

// sim bits (<<32) for the undirected edge between means a and b. Bitwise
// symmetric -> ONE exp serves both endpoints; only the tiebreak low word
// (NPIX-lb) is per-side. sim in (0,1] -> bits 62-63 free -> they carry the
// level tag (atomicMax monotone in tag -> no zeroing between levels).
__device__ __forceinline__ u64 d_simbits(float4 a, float4 b) {
  float d0 = __fsub_rn(a.x, b.x);
  float d1 = __fsub_rn(a.y, b.y);
  float d2 = __fsub_rn(a.z, b.z);
  float ss = __fadd_rn(__fadd_rn(__fmul_rn(d0, d0), __fmul_rn(d1, d1)), __fmul_rn(d2, d2));
  float dc = __fsqrt_rn(__fadd_rn(ss, 1e-12f));
  float ge = __fmul_rn(0.5f, __fadd_rn(a.w, b.w));
  float t = __fadd_rn(__fdiv_rn(dc, 10.0f), __fdiv_rn(ge, 27.8f));
  float sim = (float)exp(-(double)t);   // ~correctly-rounded expf
  return ((u64)__float_as_uint(sim)) << 32;
}

// FUSED prep + level-0 edge + level-0 scan/merge. Level 0 is a pure function
// of feat, so BOTH sides of a pair compute the same mutual decision
// independently (bit-identical: same colg inputs, same sim sequences, max is
// order-independent) and each writes only ITS OWN slot -> no cross-tile
// writes, no races, and no separate level-0 scan/merge dispatch.
//   halo: colg on 36x12 (partner v is 1 off-tile; v's edges reach 2).
//   phase A: own-key build, right/down sims shared via LDS atomics; the
//            final key is ALSO written to bnkey[idx] (tag 0, coalesced) --
//            this (re)initializes the single key buffer each chunk/replay,
//            which the tag scheme requires (stale tag-1..3 entries would
//            alias sp's tag check).
//   phase B: publish full keys in LDS; decode v; key(v) = LDS if in-tile,
//            else solo recompute from halo; mutual test; per-slot writes:
//            rep (n<v): labels=n cnt=2 mcol4=mean mem={0,v-n}
//            absorbed : labels=v cnt=0 mcol4=pix
//            unpaired : labels=n cnt=1 mcol4=pix
__global__ __launch_bounds__(256) void k_prep0(const float* __restrict__ feat,
                                               int* __restrict__ labels,
                                               int* __restrict__ cnt,
                                               float4* __restrict__ pix4,
                                               float4* __restrict__ mcol4,
                                               u16* __restrict__ mem,
                                               u64* __restrict__ bnkey) {
  __shared__ float4 scolg[432];   // 36 x 12: cx in [-2,33], cy in [-2,9]
  __shared__ u64 skey[256];
  int bb, x0, y0;
  tile_coords(bb, x0, y0);
  const float* fb = feat + (size_t)bb * 3 * NPIX;
  int tid = (int)threadIdx.x;
  skey[tid] = 0;
  for (int c = tid; c < 432; c += 256) {
    int cx = (c % 36) - 2, cy = (c / 36) - 2;
    int x = x0 + cx, y = y0 + cy;
    if (x >= 0 && x < WW && y >= 0 && y < HH) {
      float col[3];
      float g = d_colg(fb, y * WW + x, x, y, col);
      scolg[c] = make_float4(col[0], col[1], col[2], g);
    }
  }
  __syncthreads();
  int tx = tid & 31, ty = tid >> 5;
  int x = x0 + tx, y = y0 + ty;
  int n = y * WW + x;
  int idx = (bb << NSH) + n;
  int cc = (ty + 2) * 36 + (tx + 2);
  float4 ca = scolg[cc];
  pix4[idx] = ca;
  u64 key = 0;
  if (x < WW - 1) {              // right edge (shared in-tile)
    u64 s = d_simbits(ca, scolg[cc + 1]);
    key = umax64(key, s | (u32)(NPIX - (n + 1)));
    if (tx < 31) atomicMax(&skey[tid + 1], s | (u32)(NPIX - n));
  }
  if (tx == 0 && x > 0)          // left boundary edge (solo)
    key = umax64(key, d_simbits(ca, scolg[cc - 1]) | (u32)(NPIX - (n - 1)));
  if (y < HH - 1) {              // down edge (shared in-tile)
    u64 s = d_simbits(ca, scolg[cc + 36]);
    key = umax64(key, s | (u32)(NPIX - (n + WW)));
    if (ty < 7) atomicMax(&skey[tid + 32], s | (u32)(NPIX - n));
  }
  if (ty == 0 && y > 0)          // up boundary edge (solo)
    key = umax64(key, d_simbits(ca, scolg[cc - 36]) | (u32)(NPIX - (n - WW)));
  __syncthreads();
  key = umax64(key, skey[tid]);  // own-slot read/write only -> no hazard
  bnkey[idx] = key;              // tag-0 init of the single key buffer
  skey[tid] = key;               // publish full key for in-tile lookups
  __syncthreads();

  int v = NPIX - (int)(key & 0xffffffffu);   // every pixel has >=2 edges -> valid
  int vx = v & (WW - 1), vy = v >> 9;
  u64 kv;
  if (vx >= x0 && vx < x0 + 32 && vy >= y0 && vy < y0 + 8) {
    kv = skey[(vy - y0) * 32 + (vx - x0)];
  } else {
    int vc = (vy - y0 + 2) * 36 + (vx - x0 + 2);
    float4 cv = scolg[vc];
    kv = 0;
    if (vx < WW - 1) kv = umax64(kv, d_simbits(cv, scolg[vc + 1]) | (u32)(NPIX - (v + 1)));
    if (vx > 0)      kv = umax64(kv, d_simbits(cv, scolg[vc - 1]) | (u32)(NPIX - (v - 1)));
    if (vy < HH - 1) kv = umax64(kv, d_simbits(cv, scolg[vc + 36]) | (u32)(NPIX - (v + WW)));
    if (vy > 0)      kv = umax64(kv, d_simbits(cv, scolg[vc - 36]) | (u32)(NPIX - (v - WW)));
  }
  bool mutual = (NPIX - (int)(kv & 0xffffffffu)) == n;
  if (mutual) {
    if (n < v) {   // rep side: ascending-order mean (n then v), exact sequence
      float4 pb = scolg[(vy - y0 + 2) * 36 + (vx - x0 + 2)];
      float s0 = __fadd_rn(__fadd_rn(0.f, ca.x), pb.x);
      float s1 = __fadd_rn(__fadd_rn(0.f, ca.y), pb.y);
      float s2 = __fadd_rn(__fadd_rn(0.f, ca.z), pb.z);
      float sg = __fadd_rn(__fadd_rn(0.f, ca.w), pb.w);
      mcol4[idx] = make_float4(__fdiv_rn(s0, 2.0f), __fdiv_rn(s1, 2.0f),
                               __fdiv_rn(s2, 2.0f), __fdiv_rn(sg, 2.0f));
      labels[idx] = n;
      cnt[idx] = 2;
      u16* mo = mem + ((size_t)idx << 4);
      mo[0] = 0; mo[1] = (u16)(v - n);
    } else {       // absorbed side
      labels[idx] = v;
      cnt[idx] = 0;
      mcol4[idx] = ca;
    }
  } else {
    labels[idx] = n;
    cnt[idx] = 1;
    mcol4[idx] = ca;
  }
}

// levels >=1 edge pass: 32x8 tile, mean gather via labels, right/down sims
// shared via LDS atomics, horizontal RUN-LEADER DEDUP of the global atomics
// (one atomicMax per same-label run instead of one per pixel). Max over the
// same set -> bit-identical.
__global__ __launch_bounds__(256) void k_edge(const int* __restrict__ labels,
                                              const float4* __restrict__ mcol4,
                                              u64* __restrict__ bnkey, int lvl) {
  __shared__ int sla[256];
  __shared__ float4 sma[256];
  __shared__ u64 skey[256];
  int bb, x0, y0;
  tile_coords(bb, x0, y0);
  int tid = (int)threadIdx.x;
  int tx = tid & 31, ty = tid >> 5;
  int x = x0 + tx, y = y0 + ty;
  int n = y * WW + x;
  int base = bb << NSH;
  int idx = base + n;
  int la = labels[idx];
  float4 ma = mcol4[base + la];
  sla[tid] = la;
  sma[tid] = ma;
  skey[tid] = 0;
  __syncthreads();
  u64 key = 0;
  if (x < WW - 1) {              // right edge
    if (tx < 31) {
      int lb = sla[tid + 1];
      if (lb != la) {
        u64 s = d_simbits(ma, sma[tid + 1]);
        key = umax64(key, s | (u32)(NPIX - lb));
        atomicMax(&skey[tid + 1], s | (u32)(NPIX - la));
      }
    } else {
      int lb = labels[idx + 1];
      if (lb != la) key = umax64(key, d_simbits(ma, mcol4[base + lb]) | (u32)(NPIX - lb));
    }
  }
  if (tx == 0 && x > 0) {        // left boundary edge (solo)
    int lb = labels[idx - 1];
    if (lb != la) key = umax64(key, d_simbits(ma, mcol4[base + lb]) | (u32)(NPIX - lb));
  }
  if (y < HH - 1) {              // down edge
    if (ty < 7) {
      int lb = sla[tid + 32];
      if (lb != la) {
        u64 s = d_simbits(ma, sma[tid + 32]);
        key = umax64(key, s | (u32)(NPIX - lb));
        atomicMax(&skey[tid + 32], s | (u32)(NPIX - la));
      }
    } else {
      int lb = labels[idx + WW];
      if (lb != la) key = umax64(key, d_simbits(ma, mcol4[base + lb]) | (u32)(NPIX - lb));
    }
  }
  if (ty == 0 && y > 0) {        // up boundary edge (solo)
    int lb = labels[idx - WW];
    if (lb != la) key = umax64(key, d_simbits(ma, mcol4[base + lb]) | (u32)(NPIX - lb));
  }
  __syncthreads();
  // final per-pixel value; each thread reads only its OWN skey slot, so the
  // immediate overwrite below is race-free. One extra barrier publishes all
  // vals for the leader walk.
  u64 val = umax64(key, skey[tid]);
  skey[tid] = val;
  __syncthreads();
  bool leader = (tx == 0) || (sla[tid - 1] != la);
  if (leader) {
    u64 m = val;
    int t = tid + 1, txx = tx + 1;
    while (txx < 32 && sla[t] == la) { m = umax64(m, skey[t]); ++t; ++txx; }
    if (m) atomicMax(&bnkey[base + la], ((u64)lvl << 62) | m);
  }
}

// fused scan + pair processing with LDS-level compaction, levels 1-3.
// Scan reads ONLY bnkey (tag==lvl <=> live rep with level-lvl edges);
// c/cb counts read in the pairs phase only. Only v-side members are
// relabeled (rep-side members already carry label n: a region's rep is
// invariantly its min id). LAST level writes forwarding markers
// cnt[absorbed] = -newrep (k_out resolves).
template<bool LAST>
__global__ __launch_bounds__(256) void k_scanpairs(int* __restrict__ labels,
                                                   int* __restrict__ cnt,
                                                   u16* __restrict__ mem,
                                                   const u64* __restrict__ bnkey,
                                                   const float4* __restrict__ pix4,
                                                   float4* __restrict__ mcol4,
                                                   int total, int lvl) {
  __shared__ u64 swl[256];
  __shared__ int scnt;
  if (threadIdx.x == 0) scnt = 0;
  __syncthreads();

  int idx = swz_idx();
  bool pred = false;
  u64 e = 0;
  if (idx < total) {
    int n = idx & (NPIX - 1);
    int base = idx - n;
    u64 K = bnkey[idx];
    if ((int)(K >> 62) == lvl) {             // tag==lvl => live rep
      int v = NPIX - (int)(K & 0xffffffffu);
      if (v < NPIX && n < v) {               // only the min side acts
        u64 Kv = bnkey[base + v];
        if ((int)(Kv >> 62) == lvl && NPIX - (int)(Kv & 0xffffffffu) == n) {
          pred = true;
          e = ((u64)(u32)idx << 32) | (u32)v;
        }
      }
    }
  }

  u64 mask = __ballot(pred);
  int lane = (int)(threadIdx.x & 63);
  int wb0 = 0;
  if (lane == 0 && mask) wb0 = atomicAdd(&scnt, __popcll(mask));
  int wb = __shfl(wb0, 0);
  if (pred) {
    int pos = wb + __popcll(mask & ((1ull << lane) - 1ull));
    swl[pos] = e;
  }
  __syncthreads();
  int m = scnt;
  if ((int)threadIdx.x >= m) return;

  e = swl[threadIdx.x];
  int idx2 = (int)(e >> 32);
  int v = (int)(e & 0xffffffffu);
  int n = idx2 & (NPIX - 1);
  int base = idx2 - n;
  u16* mo = mem + ((size_t)idx2 << 4);
  int c = cnt[idx2];
  int cb = cnt[base + v];
  const u16* ma = mem + ((size_t)idx2 << 4);
  const u16* mb = mem + ((size_t)(base + v) << 4);
  int k = c + cb;
  float s0 = 0.f, s1 = 0.f, s2 = 0.f, sg = 0.f;
  int i = 0, j = 0;
  while (i < c || j < cb) {
    int av = (i < c) ? ((c == 1) ? n : n + (int)ma[i]) : 0x7fffffff;
    int bv = (j < cb) ? ((cb == 1) ? v : v + (int)mb[j]) : 0x7fffffff;
    int x;
    bool fromB;
    if (av < bv) { x = av; ++i; fromB = false; } else { x = bv; ++j; fromB = true; }
    float4 p = pix4[base + x];
    s0 = __fadd_rn(s0, p.x);
    s1 = __fadd_rn(s1, p.y);
    s2 = __fadd_rn(s2, p.z);
    sg = __fadd_rn(sg, p.w);
    if (!LAST && fromB) labels[base + x] = n;   // rep-side already labeled n
  }
  if (!LAST) {
    // descending in-place merged-list write. Write index t2=i2+j2+1 >= i2
    // and ma[i2] is read before mo[t2] is written -> no unread own-entry
    // clobbered.
    int i2 = c - 1, j2 = cb - 1;
    for (int t2 = k - 1; t2 >= 0; --t2) {
      int av = (i2 >= 0) ? ((c == 1) ? n : n + (int)ma[i2]) : (int)0x80000000;
      int bv = (j2 >= 0) ? ((cb == 1) ? v : v + (int)mb[j2]) : (int)0x80000000;
      int x;
      if (av > bv) { x = av; --i2; } else { x = bv; --j2; }
      mo[t2] = (u16)(x - n);
    }
  }
  float safe = (float)k;
  mcol4[idx2] = make_float4(__fdiv_rn(s0, safe), __fdiv_rn(s1, safe),
                            __fdiv_rn(s2, safe), __fdiv_rn(sg, safe));
  if (LAST) {
    cnt[base + v] = -n;          // forwarding marker for k_out
  } else {
    cnt[idx2] = k;
    cnt[base + v] = 0;
  }
}

// write labels (as f32) + region-mean color map. Resolves the LAST-level
// forwarding marker: cnt[l] <= 0 means l was absorbed at the final level by
// rep -cnt[l].
__global__ __launch_bounds__(256) void k_out(const int* __restrict__ labels,
                                             const int* __restrict__ cnt,
                                             const float4* __restrict__ mcol4,
                                             float* __restrict__ out, int total,
                                             int b0, int Btot) {
  int idx = swz_idx();
  if (idx >= total) return;
  int b = idx >> NSH;
  int n = idx & (NPIX - 1);
  int base = b << NSH;
  int l = labels[idx];
  int c2 = cnt[base + l];
  if (c2 <= 0) l = -c2;
  out[(size_t)(b0 + b) * NPIX + n] = (float)l;
  size_t cb = (size_t)Btot * NPIX;
  float4 m = mcol4[base + l];
  out[cb + ((size_t)(b0 + b) * 3 + 0) * NPIX + n] = m.x;
  out[cb + ((size_t)(b0 + b) * 3 + 1) * NPIX + n] = m.y;
  out[cb + ((size_t)(b0 + b) * 3 + 2) * NPIX + n] = m.z;
}

extern "C" void kernel_launch(void* const* d_in, const int* in_sizes, int n_in,
                              void* d_out, int out_size, void* d_ws, size_t ws_size,
                              hipStream_t stream) {
  const float* feat = (const float*)d_in[0];
  float* out = (float*)d_out;
  int Btot = in_sizes[0] / (3 * NPIX);

  // per-pixel ws bytes:
  //   mcol4 16 + pix4 16 + key 8 + labels 4 + cnt 4 + mem(u16x16) 32 = 80
  const size_t perB = (size_t)NPIX * 80;
  int nbmax = (int)(ws_size / perB);
  if (nbmax < 1) nbmax = 1;
  if (nbmax > Btot) nbmax = Btot;

  for (int b0 = 0; b0 < Btot; b0 += nbmax) {
    int nb = (Btot - b0 < nbmax) ? (Btot - b0) : nbmax;
    size_t cn = (size_t)nb << NSH;
    char* p = (char*)d_ws;
    float4* mcol4 = (float4*)p; p += cn * 16;   // 16B-aligned first
    float4* pix4 = (float4*)p;  p += cn * 16;
    u64* key = (u64*)p;         p += cn * 8;
    int* labels = (int*)p;      p += cn * 4;
    int* cnt = (int*)p;         p += cn * 4;
    u16* mem = (u16*)p;

    const float* fchunk = feat + (size_t)b0 * 3 * NPIX;
    int total = (int)cn;
    int grid = total >> 8;    // nb*1024 blocks, divisible by 8 (swizzle req.)

    k_prep0<<<grid, 256, 0, stream>>>(fchunk, labels, cnt, pix4, mcol4, mem, key);
    k_edge<<<grid, 256, 0, stream>>>(labels, mcol4, key, 1);
    k_scanpairs<false><<<grid, 256, 0, stream>>>(labels, cnt, mem, key,
                                                 pix4, mcol4, total, 1);
    k_edge<<<grid, 256, 0, stream>>>(labels, mcol4, key, 2);
    k_scanpairs<false><<<grid, 256, 0, stream>>>(labels, cnt, mem, key,
                                                 pix4, mcol4, total, 2);
    k_edge<<<grid, 256, 0, stream>>>(labels, mcol4, key, 3);
    k_scanpairs<true><<<grid, 256, 0, stream>>>(labels, cnt, mem, key,
                                                pix4, mcol4, total, 3);
    k_out<<<grid, 256, 0, stream>>>(labels, cnt, mcol4, out, total, b0, Btot);
  }
}